// Round 1
// baseline (418.020 us; speedup 1.0000x reference)
//
#include <hip/hip_runtime.h>

// N = 8192 fixed by the problem. Output layout: [0, N) = f_self = 1 - x;
// [N, N + N*N) = f_nbr = -(x_i * A_ij * x_j), row-major.
constexpr int N = 8192;
constexpr int N4 = N / 4;          // 2048 float4 per row
constexpr int TOTAL4 = (N / 4) * N; // 16,777,216 float4 elements of f_nbr

__global__ __launch_bounds__(256) void dynamics_mak_kernel(
    const float* __restrict__ x,
    const float* __restrict__ A,
    float* __restrict__ out) {
    const int tid = blockIdx.x * blockDim.x + threadIdx.x;  // one float4 each

    // f_nbr: row i is wave-uniform (2048 float4/row, 32 waves/row)
    const int row  = tid >> 11;     // / 2048
    const int col4 = tid & 2047;    // % 2048

    const float  nxi = -x[row];     // fold the negation into the broadcast scalar
    const float4 a4  = reinterpret_cast<const float4*>(A)[tid];
    const float4 xj4 = reinterpret_cast<const float4*>(x)[col4];

    float4 r;
    r.x = nxi * a4.x * xj4.x;
    r.y = nxi * a4.y * xj4.y;
    r.z = nxi * a4.z * xj4.z;
    r.w = nxi * a4.w * xj4.w;

    // out + N is 32768 B offset -> 16 B aligned, float4 store is safe
    reinterpret_cast<float4*>(out + N)[tid] = r;

    // f_self = 1 - x, folded into the first 2048 threads
    if (tid < N4) {
        const float4 xv = reinterpret_cast<const float4*>(x)[tid];
        float4 s;
        s.x = 1.0f - xv.x;
        s.y = 1.0f - xv.y;
        s.z = 1.0f - xv.z;
        s.w = 1.0f - xv.w;
        reinterpret_cast<float4*>(out)[tid] = s;
    }
}

extern "C" void kernel_launch(void* const* d_in, const int* in_sizes, int n_in,
                              void* d_out, int out_size, void* d_ws, size_t ws_size,
                              hipStream_t stream) {
    // setup_inputs order: t (scalar, unused), x [N], A [N*N]
    const float* x = reinterpret_cast<const float*>(d_in[1]);
    const float* A = reinterpret_cast<const float*>(d_in[2]);
    float* out = reinterpret_cast<float*>(d_out);

    constexpr int block = 256;
    constexpr int grid = TOTAL4 / block;  // 65536 blocks
    dynamics_mak_kernel<<<grid, block, 0, stream>>>(x, A, out);
}